// Round 10
// baseline (675.192 us; speedup 1.0000x reference)
//
#include <hip/hip_runtime.h>
#include <math.h>

#define D 32
#define ROWU 16           // uints per bf16 row (32 bf16 = 64 B)
#define NBK 1024          // bucket slots per segment
#define BSHIFT 8          // bucket = node >> 8  (256 nodes per bucket)
#define TILE_H 16384      // undirected edges per hist block
#define TILE_BIN 2048     // undirected edges per bin block (8 per thread)
#define BCAP 7680         // LDS packed-entry capacity in bucket_csr
#define RSH 15            // source-range shift: range = src >> 15 (32768 nodes/range)
#define MAXR 8            // max ranges supported (N < 2^18)

typedef unsigned int u32;
typedef unsigned short u16;

__device__ __forceinline__ float logsigf(float x) {
  return fminf(x, 0.f) - log1pf(expf(-fabsf(x)));
}

// ---- bf16 helpers (storage bf16, math fp32) ----
__device__ __forceinline__ float lo16(u32 u) { return __uint_as_float(u << 16); }
__device__ __forceinline__ float hi16(u32 u) { return __uint_as_float(u & 0xFFFF0000u); }
__device__ __forceinline__ u32 pk2(float a, float b) {  // RNE pack
  u32 ua = __float_as_uint(a), ub = __float_as_uint(b);
  u32 ra = (ua + 0x7FFFu + ((ua >> 16) & 1u)) >> 16;
  u32 rb = (ub + 0x7FFFu + ((ub >> 16) & 1u)) >> 16;
  return (ra & 0xFFFFu) | (rb << 16);
}
__device__ __forceinline__ float bfat(const u16* __restrict__ p, size_t off) {
  return __uint_as_float(((u32)p[off]) << 16);
}
__device__ __forceinline__ void accum8(float* a, float w, uint4 x) {
  a[0] += w * lo16(x.x); a[1] += w * hi16(x.x);
  a[2] += w * lo16(x.y); a[3] += w * hi16(x.y);
  a[4] += w * lo16(x.z); a[5] += w * hi16(x.z);
  a[6] += w * lo16(x.w); a[7] += w * hi16(x.w);
}
__device__ __forceinline__ uint4 pack8(const float* a, float w) {
  return make_uint4(pk2(w * a[0], w * a[1]), pk2(w * a[2], w * a[3]),
                    pk2(w * a[4], w * a[5]), pk2(w * a[6], w * a[7]));
}

// sub-range bounds for node n of segment segN (= seg*N): range r of nr
__device__ __forceinline__ int2 rbounds(const int* __restrict__ rp,
                                        const int* __restrict__ mids,
                                        size_t segN, int n, int r, int nr) {
  int b0 = (r == 0) ? rp[n] : mids[(segN + n) * (MAXR - 1) + (r - 1)];
  int b1 = (r == nr - 1) ? rp[n + 1] : mids[(segN + n) * (MAXR - 1) + r];
  return make_int2(b0, b1);
}

// ================= CSR build via bucket binning =================
// seg 0 = tgt, 1 = aux0, 2 = aux1. Directed entry packed: (dst_local<<18)|src.

__global__ void hist_kernel(const int2* __restrict__ tgt, const int2* __restrict__ aux,
                            int E, int Nu, int BPS, int* __restrict__ bcur) {
  __shared__ int lh[NBK];
  int seg = blockIdx.x / BPS;
  int blk = blockIdx.x - seg * BPS;
  const int2* edges = (seg == 0) ? tgt : aux + (size_t)(seg - 1) * E;
  for (int b = threadIdx.x; b < NBK; b += 256) lh[b] = 0;
  __syncthreads();
  int e0 = blk * TILE_H;
  for (int k = threadIdx.x; k < TILE_H; k += 256) {
    int e = e0 + k;
    if (e < E) {
      int2 ed = edges[e];
      atomicAdd(&lh[ed.x >> BSHIFT], 1);
      atomicAdd(&lh[(ed.y + Nu) >> BSHIFT], 1);
    }
  }
  __syncthreads();
  for (int b = threadIdx.x; b < NBK; b += 256)
    if (lh[b]) atomicAdd(&bcur[seg * NBK + b], lh[b]);
}

__global__ void bscan_kernel(int* __restrict__ bcur) {
  int* b = bcur + blockIdx.x * NBK;
  int lane = threadIdx.x;
  int carry = 0;
  for (int base = 0; base < NBK; base += 64) {
    int i = base + lane;
    int v = b[i];
    int s = v;
    #pragma unroll
    for (int o = 1; o < 64; o <<= 1) {
      int t = __shfl_up(s, o);
      if (lane >= o) s += t;
    }
    b[i] = carry + s - v;
    carry += __shfl(s, 63);
  }
}

__global__ void bin_kernel(const int2* __restrict__ tgt, const int2* __restrict__ aux,
                           int E, int Nu, int BPS, int* __restrict__ bcur,
                           int* __restrict__ binned) {
  __shared__ int stage[2 * TILE_BIN];
  __shared__ int lh[NBK];
  __shared__ int loff[NBK];
  __shared__ int gb[NBK];
  __shared__ int wred[4];
  __shared__ int stot;
  int seg = blockIdx.x / BPS;
  int blk = blockIdx.x - seg * BPS;
  const int2* edges = (seg == 0) ? tgt : aux + (size_t)(seg - 1) * E;
  int* out = binned + (size_t)seg * 2 * E;
  int tid = threadIdx.x;
  for (int b = tid; b < NBK; b += 256) lh[b] = 0;
  __syncthreads();
  int e0 = blk * TILE_BIN;
  int pkv[16];
  int pb[16];
  int pr[16];
  #pragma unroll
  for (int it = 0; it < 8; ++it) {
    int e = e0 + tid + it * 256;
    bool ok = e < E;
    int2 ed = ok ? edges[e] : make_int2(0, -Nu);
    int u = ed.x, v = ed.y + Nu;
    int b1 = u >> BSHIFT, b2 = v >> BSHIFT;
    pkv[2 * it] = ((u & 255) << 18) | v;
    pb[2 * it] = b1;
    pr[2 * it] = ok ? atomicAdd(&lh[b1], 1) : 0;
    pkv[2 * it + 1] = ((v & 255) << 18) | u;
    pb[2 * it + 1] = b2;
    pr[2 * it + 1] = ok ? atomicAdd(&lh[b2], 1) : 0;
  }
  __syncthreads();
  int lane = tid & 63, wid = tid >> 6;
  int b4 = tid * 4;
  int v0 = lh[b4], v1 = lh[b4 + 1], v2 = lh[b4 + 2], v3 = lh[b4 + 3];
  int tsum = v0 + v1 + v2 + v3;
  int incl = tsum;
  #pragma unroll
  for (int o = 1; o < 64; o <<= 1) {
    int t = __shfl_up(incl, o);
    if (lane >= o) incl += t;
  }
  if (lane == 63) wred[wid] = incl;
  __syncthreads();
  int wbase = 0;
  for (int w = 0; w < wid; ++w) wbase += wred[w];
  int excl = wbase + incl - tsum;
  loff[b4] = excl;
  loff[b4 + 1] = excl + v0;
  loff[b4 + 2] = excl + v0 + v1;
  loff[b4 + 3] = excl + v0 + v1 + v2;
  if (tid == 255) stot = excl + tsum;
  #pragma unroll
  for (int j = 0; j < 4; ++j) {
    int b = b4 + j;
    int c = lh[b];
    gb[b] = c ? atomicAdd(&bcur[seg * NBK + b], c) : 0;
  }
  __syncthreads();
  #pragma unroll
  for (int it = 0; it < 16; ++it) {
    int e = e0 + tid + (it >> 1) * 256;
    if (e < E) stage[loff[pb[it]] + pr[it]] = pkv[it];
  }
  __syncthreads();
  int tot = stot;
  for (int k = tid; k < tot; k += 256) {
    int lo = 0, hi = NBK;
    while (lo < hi) {
      int mid = (lo + hi) >> 1;
      if (loff[mid] <= k) lo = mid + 1; else hi = mid;
    }
    int b = lo - 1;
    out[gb[b] + (k - loff[b])] = stage[k];
  }
}

// one block per (seg,bucket): counting sort over (local_node, src_range) ->
// deg, rowptr, per-node range mid-pointers, node+range-sorted col.
__global__ void bucket_csr_kernel(const int* __restrict__ binned,
                                  const int* __restrict__ bend, int E2, int N, int NBKe,
                                  int nr, int* __restrict__ deg3, int* __restrict__ rp3,
                                  int* __restrict__ mids, int* __restrict__ col_all) {
  __shared__ int ent[BCAP];
  __shared__ int cnt[256 * MAXR];
  __shared__ int off[256 * MAXR];
  __shared__ int wred[4];
  int seg = blockIdx.x / NBKe;
  int bkt = blockIdx.x - seg * NBKe;
  int node0 = bkt << BSHIFT;
  const int* bc = bend + seg * NBK;
  int start = (bkt == 0) ? 0 : bc[bkt - 1];
  int end = bc[bkt];
  int cntE = end - start;
  const int* src = binned + (size_t)seg * E2 + start;
  bool inLds = (cntE <= BCAP);
  if (inLds)
    for (int k = threadIdx.x; k < cntE; k += 256) ent[k] = src[k];
  for (int k = threadIdx.x; k < 256 * nr; k += 256) cnt[k] = 0;
  __syncthreads();
  for (int k = threadIdx.x; k < cntE; k += 256) {
    int en = inLds ? ent[k] : src[k];
    int key = (en >> 18) * nr + ((en & 0x3FFFF) >> RSH);
    atomicAdd(&cnt[key], 1);
  }
  __syncthreads();
  int lane = threadIdx.x & 63, wid = threadIdx.x >> 6;
  int tot = 0;
  for (int r = 0; r < nr; ++r) tot += cnt[threadIdx.x * nr + r];
  int incl = tot;
  #pragma unroll
  for (int o = 1; o < 64; o <<= 1) {
    int t = __shfl_up(incl, o);
    if (lane >= o) incl += t;
  }
  if (lane == 63) wred[wid] = incl;
  __syncthreads();
  int wbase = 0;
  for (int w = 0; w < wid; ++w) wbase += wred[w];
  int excl = wbase + incl - tot;  // node-level exclusive offset within bucket
  int run = excl;
  for (int r = 0; r < nr; ++r) {
    off[threadIdx.x * nr + r] = run;
    run += cnt[threadIdx.x * nr + r];
  }
  int node = node0 + (int)threadIdx.x;
  if (node < N) {
    deg3[(size_t)seg * N + node] = tot;
    rp3[(size_t)seg * (N + 1) + node] = start + excl;
    int* m = mids + ((size_t)seg * N + node) * (MAXR - 1);
    int acc = excl;
    for (int r = 1; r < nr; ++r) {
      acc += cnt[threadIdx.x * nr + r - 1];
      m[r - 1] = start + acc;
    }
  }
  if (bkt == 0 && threadIdx.x == 0) rp3[(size_t)seg * (N + 1) + N] = E2;
  __syncthreads();
  for (int k = threadIdx.x; k < 256 * nr; k += 256) cnt[k] = 0;
  __syncthreads();
  int* col = col_all + (size_t)seg * E2 + start;
  for (int k = threadIdx.x; k < cntE; k += 256) {
    int en = inLds ? ent[k] : src[k];
    int s_ = en & 0x3FFFF;
    int key = (en >> 18) * nr + (s_ >> RSH);
    int pos = atomicAdd(&cnt[key], 1);
    col[off[key] + pos] = s_;
  }
}

__global__ void dinv_all_kernel(const int* __restrict__ deg3, float* __restrict__ dinv5,
                                int N) {
  int n = blockIdx.x * blockDim.x + threadIdx.x;
  if (n >= N) return;
  int dt = deg3[n], d0 = deg3[N + n], d1 = deg3[2 * N + n];
  dinv5[n]         = dt ? rsqrtf((float)dt) : 0.f;
  dinv5[N + n]     = d0 ? rsqrtf((float)d0) : 0.f;
  dinv5[2 * N + n] = d1 ? rsqrtf((float)d1) : 0.f;
  int c0 = dt + d0, c1 = dt + d1;
  dinv5[3 * N + n] = c0 ? rsqrtf((float)c0) : 0.f;
  dinv5[4 * N + n] = c1 ? rsqrtf((float)c1) : 0.f;
}

__global__ void cvt_emb_kernel(const float2* __restrict__ ue, long nu2,
                               const float2* __restrict__ ie, long ni2,
                               u32* __restrict__ emb) {
  long i = (long)blockIdx.x * blockDim.x + threadIdx.x;
  if (i >= nu2 + ni2) return;
  float2 v = (i < nu2) ? ue[i] : ie[i - nu2];
  emb[i] = pk2(v.x, v.y);
}

// ================= dense propagation (bf16 rows, range-blocked) =================

// layer-1 for BOTH idx; range-major so each phase touches a 2 MB EMB slice.
__global__ void gather_fused_all_kernel(const int* __restrict__ rp3,
                                        const int* __restrict__ col_all,
                                        const int* __restrict__ mids,
                                        const float* __restrict__ dinv5,
                                        const uint4* __restrict__ emb,
                                        uint4* __restrict__ BaAll, uint4* __restrict__ BcAll,
                                        int N, int E2, int nr) {
  const int* rpA0 = rp3 + (size_t)1 * (N + 1);
  const int* rpA1 = rp3 + (size_t)2 * (N + 1);
  const int* colA0 = col_all + (size_t)1 * E2;
  const int* colA1 = col_all + (size_t)2 * E2;
  const float* dvA0 = dinv5 + (size_t)1 * N;
  const float* dvA1 = dinv5 + (size_t)2 * N;
  const float* dvC0 = dinv5 + (size_t)3 * N;
  const float* dvC1 = dinv5 + (size_t)4 * N;
  int t = blockIdx.x * blockDim.x + threadIdx.x;
  int n = t >> 2;
  if (n >= N) return;
  int lane = t & 3;
  float aA0[8] = {0, 0, 0, 0, 0, 0, 0, 0};
  float aA1[8] = {0, 0, 0, 0, 0, 0, 0, 0};
  float aC0[8] = {0, 0, 0, 0, 0, 0, 0, 0};
  float aC1[8] = {0, 0, 0, 0, 0, 0, 0, 0};
  for (int r = 0; r < nr; ++r) {
    // aux0 range r
    int2 b = rbounds(rpA0, mids, (size_t)1 * N, n, r, nr);
    int j = b.x;
    for (; j + 1 < b.y; j += 2) {
      int c0 = colA0[j], c1 = colA0[j + 1];
      float wa0 = dvA0[c0], wc0 = dvC0[c0];
      float wa1 = dvA0[c1], wc1 = dvC0[c1];
      uint4 x0 = emb[(size_t)c0 * 4 + lane];
      uint4 x1 = emb[(size_t)c1 * 4 + lane];
      accum8(aA0, wa0, x0); accum8(aC0, wc0, x0);
      accum8(aA0, wa1, x1); accum8(aC0, wc1, x1);
    }
    if (j < b.y) {
      int c = colA0[j];
      float wa = dvA0[c], wc = dvC0[c];
      uint4 x = emb[(size_t)c * 4 + lane];
      accum8(aA0, wa, x); accum8(aC0, wc, x);
    }
    // aux1 range r
    b = rbounds(rpA1, mids, (size_t)2 * N, n, r, nr);
    j = b.x;
    for (; j + 1 < b.y; j += 2) {
      int c0 = colA1[j], c1 = colA1[j + 1];
      float wa0 = dvA1[c0], wc0 = dvC1[c0];
      float wa1 = dvA1[c1], wc1 = dvC1[c1];
      uint4 x0 = emb[(size_t)c0 * 4 + lane];
      uint4 x1 = emb[(size_t)c1 * 4 + lane];
      accum8(aA1, wa0, x0); accum8(aC1, wc0, x0);
      accum8(aA1, wa1, x1); accum8(aC1, wc1, x1);
    }
    if (j < b.y) {
      int c = colA1[j];
      float wa = dvA1[c], wc = dvC1[c];
      uint4 x = emb[(size_t)c * 4 + lane];
      accum8(aA1, wa, x); accum8(aC1, wc, x);
    }
    // tgt range r (rows read once for both idx)
    b = rbounds(rp3, mids, 0, n, r, nr);
    j = b.x;
    for (; j + 1 < b.y; j += 2) {
      int c0 = col_all[j], c1 = col_all[j + 1];
      float w00 = dvC0[c0], w10 = dvC1[c0];
      float w01 = dvC0[c1], w11 = dvC1[c1];
      uint4 x0 = emb[(size_t)c0 * 4 + lane];
      uint4 x1 = emb[(size_t)c1 * 4 + lane];
      accum8(aC0, w00, x0); accum8(aC1, w10, x0);
      accum8(aC0, w01, x1); accum8(aC1, w11, x1);
    }
    if (j < b.y) {
      int c = col_all[j];
      float w0 = dvC0[c], w1 = dvC1[c];
      uint4 x = emb[(size_t)c * 4 + lane];
      accum8(aC0, w0, x); accum8(aC1, w1, x);
    }
  }
  size_t o = (size_t)n * 4 + lane;
  size_t rowN4 = (size_t)N * 4;
  BaAll[o] = pack8(aA0, dvA0[n]);
  BaAll[rowN4 + o] = pack8(aA1, dvA1[n]);
  BcAll[o] = pack8(aC0, dvC0[n]);
  BcAll[rowN4 + o] = pack8(aC1, dvC1[n]);
}

// aux L2 + avg: A(idx) = (EMB + Ba + dinv*gather(Ba))/3, interleaved out.
__global__ void gather_avg_kernel(const int* __restrict__ rp3, const int* __restrict__ col_all,
                                  const int* __restrict__ mids,
                                  const float* __restrict__ dinv5,
                                  const uint4* __restrict__ emb,
                                  const uint4* __restrict__ BaAll, uint4* __restrict__ AI,
                                  int N, int E2, int nr) {
  int idx = blockIdx.y;
  const int* rp = rp3 + (size_t)(1 + idx) * (N + 1);
  const int* col = col_all + (size_t)(1 + idx) * E2;
  const float* dv = dinv5 + (size_t)(1 + idx) * N;
  const uint4* cur = BaAll + (size_t)idx * N * 4;
  size_t segN = (size_t)(1 + idx) * N;
  int t = blockIdx.x * blockDim.x + threadIdx.x;
  int n = t >> 2;
  if (n >= N) return;
  int lane = t & 3;
  float acc[8] = {0, 0, 0, 0, 0, 0, 0, 0};
  for (int r = 0; r < nr; ++r) {
    int2 bb = rbounds(rp, mids, segN, n, r, nr);
    int j = bb.x;
    for (; j + 3 < bb.y; j += 4) {
      int c0 = col[j], c1 = col[j + 1], c2 = col[j + 2], c3 = col[j + 3];
      float w0 = dv[c0], w1 = dv[c1], w2 = dv[c2], w3 = dv[c3];
      uint4 x0 = cur[(size_t)c0 * 4 + lane];
      uint4 x1 = cur[(size_t)c1 * 4 + lane];
      uint4 x2 = cur[(size_t)c2 * 4 + lane];
      uint4 x3 = cur[(size_t)c3 * 4 + lane];
      accum8(acc, w0, x0);
      accum8(acc, w1, x1);
      accum8(acc, w2, x2);
      accum8(acc, w3, x3);
    }
    for (; j < bb.y; ++j) {
      int c = col[j];
      float w = dv[c];
      uint4 x = cur[(size_t)c * 4 + lane];
      accum8(acc, w, x);
    }
  }
  float wn = dv[n];
  uint4 e4 = emb[(size_t)n * 4 + lane];
  uint4 b4 = cur[(size_t)n * 4 + lane];
  float r8[8];
  r8[0] = (lo16(e4.x) + lo16(b4.x) + wn * acc[0]) * (1.f / 3.f);
  r8[1] = (hi16(e4.x) + hi16(b4.x) + wn * acc[1]) * (1.f / 3.f);
  r8[2] = (lo16(e4.y) + lo16(b4.y) + wn * acc[2]) * (1.f / 3.f);
  r8[3] = (hi16(e4.y) + hi16(b4.y) + wn * acc[3]) * (1.f / 3.f);
  r8[4] = (lo16(e4.z) + lo16(b4.z) + wn * acc[4]) * (1.f / 3.f);
  r8[5] = (hi16(e4.z) + hi16(b4.z) + wn * acc[5]) * (1.f / 3.f);
  r8[6] = (lo16(e4.w) + lo16(b4.w) + wn * acc[6]) * (1.f / 3.f);
  r8[7] = (hi16(e4.w) + hi16(b4.w) + wn * acc[7]) * (1.f / 3.f);
  AI[(size_t)n * 8 + idx * 4 + lane] = pack8(r8, 1.f);
}

// de layer-1 for BOTH idx in ONE tgt pass over interleaved A; range-blocked.
__global__ void de_gather_kernel(const int* __restrict__ rp3, const int* __restrict__ col_all,
                                 const int* __restrict__ mids,
                                 const float* __restrict__ dinv5,
                                 const uint4* __restrict__ AI, uint4* __restrict__ DeI,
                                 int N, int nr) {
  int t = blockIdx.x * blockDim.x + threadIdx.x;
  int n = t >> 3;
  if (n >= N) return;
  int lane = t & 7;
  float acc[8] = {0, 0, 0, 0, 0, 0, 0, 0};
  for (int r = 0; r < nr; ++r) {
    int2 b = rbounds(rp3, mids, 0, n, r, nr);
    int j = b.x;
    for (; j + 1 < b.y; j += 2) {
      int c0 = col_all[j], c1 = col_all[j + 1];
      float w0 = dinv5[c0], w1 = dinv5[c1];
      uint4 x0 = AI[(size_t)c0 * 8 + lane];
      uint4 x1 = AI[(size_t)c1 * 8 + lane];
      accum8(acc, w0, x0);
      accum8(acc, w1, x1);
    }
    if (j < b.y) {
      int c = col_all[j];
      float w = dinv5[c];
      uint4 x = AI[(size_t)c * 8 + lane];
      accum8(acc, w, x);
    }
  }
  DeI[(size_t)n * 8 + lane] = pack8(acc, dinv5[n]);
}

// ================= sparse L2 + score (bf16 rows) =================

__device__ __forceinline__ float fdim2(const int* __restrict__ rpA, const int* __restrict__ colA,
                                       const int* __restrict__ rpT, const int* __restrict__ colT,
                                       const float* __restrict__ dv,
                                       const u16* __restrict__ base, const u16* __restrict__ L1,
                                       int r, int d) {
  float acc = 0.f;
  for (int j = rpA[r]; j < rpA[r + 1]; ++j) {
    int c = colA[j];
    acc += dv[c] * bfat(L1, (size_t)c * D + d);
  }
  for (int j = rpT[r]; j < rpT[r + 1]; ++j) {
    int c = colT[j];
    acc += dv[c] * bfat(L1, (size_t)c * D + d);
  }
  return (bfat(base, (size_t)r * D + d) + bfat(L1, (size_t)r * D + d) + dv[r] * acc) * (1.f / 3.f);
}

__device__ __forceinline__ float fdim1i(const int* __restrict__ rp, const int* __restrict__ col,
                                        const float* __restrict__ dv,
                                        const u16* __restrict__ base, const u16* __restrict__ L1,
                                        int r, int di) {
  float acc = 0.f;
  for (int j = rp[r]; j < rp[r + 1]; ++j) {
    int c = col[j];
    acc += dv[c] * bfat(L1, (size_t)c * 64 + di);
  }
  return (bfat(base, (size_t)r * 64 + di) + bfat(L1, (size_t)r * 64 + di) + dv[r] * acc) * (1.f / 3.f);
}

__global__ void ce_sparse_kernel(const int* __restrict__ rp3, const int* __restrict__ col_all,
                                 const float* __restrict__ dinv5,
                                 const u32* __restrict__ EMBu, const u32* __restrict__ BcAll,
                                 const int* __restrict__ batch, int Bsz, int Nu, int N, int E2,
                                 float* __restrict__ cps, float* __restrict__ cns) {
  int idx = blockIdx.y;
  const int* rpA = rp3 + (size_t)(1 + idx) * (N + 1);
  const int* colA = col_all + (size_t)(1 + idx) * E2;
  const float* dv = dinv5 + (size_t)(3 + idx) * N;
  const u16* base = (const u16*)EMBu;
  const u16* L1 = (const u16*)(BcAll + (size_t)idx * N * ROWU);
  float* outp = cps + (size_t)idx * Bsz;
  float* outn = cns + (size_t)idx * Bsz;
  int t = blockIdx.x * blockDim.x + threadIdx.x;
  int b = t >> 5, d = t & 31;
  if (b >= Bsz) return;
  int u = batch[b * 9 + 0];
  int p = batch[b * 9 + 1] + Nu;
  int n = batch[b * 9 + 2] + Nu;
  float uv = fdim2(rpA, colA, rp3, col_all, dv, base, L1, u, d);
  float pv = fdim2(rpA, colA, rp3, col_all, dv, base, L1, p, d);
  float nv = fdim2(rpA, colA, rp3, col_all, dv, base, L1, n, d);
  float sp = uv * pv, sn = uv * nv;
  #pragma unroll
  for (int o = 16; o > 0; o >>= 1) {
    sp += __shfl_down(sp, o, 32);
    sn += __shfl_down(sn, o, 32);
  }
  if (d == 0) {
    outp[b] = fmaxf(sp, 0.f);
    outn[b] = fmaxf(sn, 0.f);
  }
}

__global__ void de_sparse_kernel(const int* __restrict__ rp3, const int* __restrict__ col_all,
                                 const float* __restrict__ dinv5,
                                 const u32* __restrict__ AI, const u32* __restrict__ DeI,
                                 const int* __restrict__ batch, int Bsz, int Nu, int N,
                                 float* __restrict__ dps, float* __restrict__ dns) {
  int idx = blockIdx.y;
  const u16* base = (const u16*)AI;
  const u16* L1 = (const u16*)DeI;
  float* outp = dps + (size_t)idx * Bsz;
  float* outn = dns + (size_t)idx * Bsz;
  int t = blockIdx.x * blockDim.x + threadIdx.x;
  int b = t >> 5, d = t & 31;
  if (b >= Bsz) return;
  int di = idx * 32 + d;
  int u = batch[b * 9 + 0];
  int p = batch[b * 9 + 1] + Nu;
  int n = batch[b * 9 + 2] + Nu;
  float uv = fdim1i(rp3, col_all, dinv5, base, L1, u, di);
  float pv = fdim1i(rp3, col_all, dinv5, base, L1, p, di);
  float nv = fdim1i(rp3, col_all, dinv5, base, L1, n, di);
  float sp = uv * pv, sn = uv * nv;
  #pragma unroll
  for (int o = 16; o > 0; o >>= 1) {
    sp += __shfl_down(sp, o, 32);
    sn += __shfl_down(sn, o, 32);
  }
  if (d == 0) {
    outp[b] = fmaxf(sp, 0.f);
    outn[b] = fmaxf(sn, 0.f);
  }
}

// ================= batch scores / losses on interleaved A (bf16) =================

__device__ __forceinline__ float dotrow(const u32* __restrict__ a, const u32* __restrict__ b) {
  float s = 0.f;
  #pragma unroll
  for (int k = 0; k < ROWU; ++k) {
    u32 x = a[k], y = b[k];
    s += lo16(x) * lo16(y) + hi16(x) * hi16(y);
  }
  return s;
}

__global__ void score_aux_kernel(const u32* __restrict__ AI, const int* __restrict__ batch,
                                 int Bsz, int Nu, int N, float* __restrict__ aps,
                                 float* __restrict__ ans_, float* __restrict__ accs) {
  int idx = blockIdx.y;
  const u32* A = AI + (size_t)idx * ROWU;  // interleaved: row r at r*32 + idx*16
  float* outp = aps + (size_t)idx * Bsz;
  float* outn = ans_ + (size_t)idx * Bsz;
  int b = blockIdx.x * blockDim.x + threadIdx.x;
  float l = 0.f;
  if (b < Bsz) {
    int u = batch[b * 9 + 0];
    int p = batch[b * 9 + 1] + Nu;
    int n = batch[b * 9 + 2] + Nu;
    const u32* ur = A + (size_t)u * 32;
    outp[b] = fmaxf(dotrow(ur, A + (size_t)p * 32), 0.f);
    outn[b] = fmaxf(dotrow(ur, A + (size_t)n * 32), 0.f);
    const int* r = batch + b * 9 + 3 * (1 + idx);
    const u32* aur = A + (size_t)r[0] * 32;
    float ps = dotrow(aur, A + (size_t)(r[1] + Nu) * 32);
    float ns = dotrow(aur, A + (size_t)(r[2] + Nu) * 32);
    l = -logsigf(ps - ns);
  }
  for (int o = 32; o > 0; o >>= 1) l += __shfl_down(l, o);
  if ((threadIdx.x & 63) == 0) atomicAdd(&accs[idx], l);
}

__global__ void recloss_kernel(const float* __restrict__ cps, const float* __restrict__ cns,
                               const float* __restrict__ aps, const float* __restrict__ ans_,
                               const float* __restrict__ dps, const float* __restrict__ dns,
                               int Bsz, int NA, float* __restrict__ acc) {
  int b = blockIdx.x * blockDim.x + threadIdx.x;
  float l = 0.f;
  if (b < Bsz) {
    float dp = 0.f, dn = 0.f, cap = 0.f, can = 0.f;
    for (int i = 0; i < NA; ++i) {
      dp += dps[i * Bsz + b];
      dn += dns[i * Bsz + b];
      cap += cps[i * Bsz + b] * aps[i * Bsz + b];
      can += cns[i * Bsz + b] * ans_[i * Bsz + b];
    }
    l = -logsigf(dp * cap - dn * can);
  }
  for (int o = 32; o > 0; o >>= 1) l += __shfl_down(l, o);
  if ((threadIdx.x & 63) == 0) atomicAdd(acc, l);
}

__global__ void sumsq2_kernel(const float4* __restrict__ xu, int n4u,
                              const float4* __restrict__ xi, int n4i,
                              float* __restrict__ accU, float* __restrict__ accI) {
  __shared__ float redU[4], redI[4];
  int tid = threadIdx.x;
  int gid = blockIdx.x * blockDim.x + tid;
  int stride = gridDim.x * blockDim.x;
  float su = 0.f, si = 0.f;
  for (int i = gid; i < n4u; i += stride) {
    float4 v = xu[i];
    su += v.x * v.x + v.y * v.y + v.z * v.z + v.w * v.w;
  }
  for (int i = gid; i < n4i; i += stride) {
    float4 v = xi[i];
    si += v.x * v.x + v.y * v.y + v.z * v.z + v.w * v.w;
  }
  for (int o = 32; o > 0; o >>= 1) {
    su += __shfl_down(su, o);
    si += __shfl_down(si, o);
  }
  if ((tid & 63) == 0) { redU[tid >> 6] = su; redI[tid >> 6] = si; }
  __syncthreads();
  if (tid == 0) {
    atomicAdd(accU, redU[0] + redU[1] + redU[2] + redU[3]);
    atomicAdd(accI, redI[0] + redI[1] + redI[2] + redI[3]);
  }
}

__global__ void final_kernel(const float* __restrict__ accs, int Bsz, int NA, int NiRows,
                             float* __restrict__ out) {
  float rec = accs[NA] / (float)Bsz;
  float aux = 0.f;
  for (int i = 0; i < NA; ++i) aux += accs[i] / (float)Bsz;
  aux /= (float)NA;
  float embl = (sqrtf(accs[NA + 1]) + sqrtf(accs[NA + 2])) / (float)NiRows;
  out[0] = rec + 0.5f * aux + 1e-4f * embl;
}

extern "C" void kernel_launch(void* const* d_in, const int* in_sizes, int n_in,
                              void* d_out, int out_size, void* d_ws, size_t ws_size,
                              hipStream_t stream) {
  const float* user_emb = (const float*)d_in[0];
  const float* item_emb = (const float*)d_in[1];
  const int* batch = (const int*)d_in[2];
  const int* aux_edges = (const int*)d_in[3];
  const int* tgt_edges = (const int*)d_in[4];

  const int NuRows = in_sizes[0] / D;          // 100001
  const int NiRows = in_sizes[1] / D;          // 50001
  const int Bsz = in_sizes[2] / 9;             // 4096
  const int E = in_sizes[4] / 2;               // 1,000,000
  const int NA = in_sizes[3] / (2 * E);        // 2
  const int N = NuRows + NiRows;               // 150002 < 2^18 (pack invariant)
  const int E2 = 2 * E;
  const size_t rowH = (size_t)N * ROWU;
  const int BPS_H = (E + TILE_H - 1) / TILE_H;
  const int BPS_B = (E + TILE_BIN - 1) / TILE_BIN;
  const int NBKe = (N + (1 << BSHIFT) - 1) >> BSHIFT;
  const int nr = ((N - 1) >> RSH) + 1;         // 5 source ranges for N=150002

  // ---- workspace layout ----
  u32* EMBu = (u32*)d_ws;                 // rowH (planar)
  u32* AI = EMBu + rowH;                  // 2*rowH (INTERLEAVED per node)
  u32* BaAll = AI + 2 * rowH;             // 2*rowH (planar aux L1; later interleaved De)
  u32* BcAll = BaAll + 2 * rowH;          // 2*rowH (planar comb L1)
  int* deg3 = (int*)(BcAll + 2 * rowH);           // 3*N
  float* dinv5 = (float*)(deg3 + 3 * (size_t)N);  // 5*N
  int* rp3 = (int*)(dinv5 + 5 * (size_t)N);       // 3*(N+1)
  int* bcur = rp3 + 3 * (size_t)(N + 1);          // 3*NBK
  int* col_all = bcur + 3 * (size_t)NBK;          // 3*2E
  int* mids = col_all + 3 * (size_t)E2;           // 3*N*(MAXR-1)
  float* cps = (float*)(mids + 3 * (size_t)N * (MAXR - 1));
  float* cns = cps + (size_t)NA * Bsz;
  float* aps = cns + (size_t)NA * Bsz;
  float* ans_ = aps + (size_t)NA * Bsz;
  float* dps = ans_ + (size_t)NA * Bsz;
  float* dns = dps + (size_t)NA * Bsz;
  float* accs = dns + (size_t)NA * Bsz;           // [NA aux][rec][sumsq_u][sumsq_i]
  int* binned = (int*)AI;  // 24 MB alias spanning AI+BaAll; dead before gathers

  const int TB = 256;
  const int gN = (N + TB - 1) / TB;
  const int gN4 = (N * 4 + TB - 1) / TB;
  const int gN8 = (N * 8 + TB - 1) / TB;
  const int gB = (Bsz + TB - 1) / TB;
  const int gB32 = (Bsz * 32 + TB - 1) / TB;
  const long nu2 = (long)NuRows * ROWU;
  const long ni2 = (long)NiRows * ROWU;
  const int gCvt = (int)((nu2 + ni2 + TB - 1) / TB);

  cvt_emb_kernel<<<gCvt, TB, 0, stream>>>((const float2*)user_emb, nu2,
                                          (const float2*)item_emb, ni2, EMBu);

  // ---- binned CSR build (node + source-range sorted) ----
  hipMemsetAsync(bcur, 0, 3 * (size_t)NBK * sizeof(int), stream);
  hist_kernel<<<3 * BPS_H, TB, 0, stream>>>((const int2*)tgt_edges, (const int2*)aux_edges,
                                            E, NuRows, BPS_H, bcur);
  bscan_kernel<<<3, 64, 0, stream>>>(bcur);
  bin_kernel<<<3 * BPS_B, TB, 0, stream>>>((const int2*)tgt_edges, (const int2*)aux_edges,
                                           E, NuRows, BPS_B, bcur, binned);
  bucket_csr_kernel<<<3 * NBKe, TB, 0, stream>>>(binned, bcur, E2, N, NBKe, nr,
                                                 deg3, rp3, mids, col_all);
  dinv_all_kernel<<<gN, TB, 0, stream>>>(deg3, dinv5, N);

  hipMemsetAsync(accs, 0, (size_t)(NA + 3) * sizeof(float), stream);

  dim3 gridG(gN4, NA), gridB(gB, NA), gridS(gB32, NA);

  gather_fused_all_kernel<<<gN4, TB, 0, stream>>>(rp3, col_all, mids, dinv5,
                                                  (const uint4*)EMBu,
                                                  (uint4*)BaAll, (uint4*)BcAll, N, E2, nr);
  gather_avg_kernel<<<gridG, TB, 0, stream>>>(rp3, col_all, mids, dinv5, (const uint4*)EMBu,
                                              (const uint4*)BaAll, (uint4*)AI, N, E2, nr);
  score_aux_kernel<<<gridB, TB, 0, stream>>>(AI, batch, Bsz, NuRows, N, aps, ans_, accs);
  ce_sparse_kernel<<<gridS, TB, 0, stream>>>(rp3, col_all, dinv5, EMBu, BcAll,
                                             batch, Bsz, NuRows, N, E2, cps, cns);
  de_gather_kernel<<<gN8, TB, 0, stream>>>(rp3, col_all, mids, dinv5, (const uint4*)AI,
                                           (uint4*)BaAll, N, nr);
  de_sparse_kernel<<<gridS, TB, 0, stream>>>(rp3, col_all, dinv5, AI, BaAll,
                                             batch, Bsz, NuRows, N, dps, dns);

  sumsq2_kernel<<<104, TB, 0, stream>>>((const float4*)user_emb,
                                        (int)((size_t)NuRows * D / 4),
                                        (const float4*)item_emb,
                                        (int)((size_t)NiRows * D / 4),
                                        accs + NA + 1, accs + NA + 2);
  recloss_kernel<<<gB, TB, 0, stream>>>(cps, cns, aps, ans_, dps, dns, Bsz, NA, accs + NA);
  final_kernel<<<1, 1, 0, stream>>>(accs, Bsz, NA, NiRows, (float*)d_out);
}

// Round 11
// 629.805 us; speedup vs baseline: 1.0721x; 1.0721x over previous
//
#include <hip/hip_runtime.h>
#include <math.h>

#define D 32
#define ROWU 16           // uints per bf16 row (32 bf16 = 64 B)
#define NBK 1024          // bucket slots per segment
#define BSHIFT 8          // bucket = node >> 8  (256 nodes per bucket)
#define TILE_H 16384      // undirected edges per hist block
#define TILE_BIN 2048     // undirected edges per bin block (8 per thread)
#define BCAP 7680         // LDS packed-entry capacity in bucket_csr

typedef unsigned int u32;
typedef unsigned short u16;

__device__ __forceinline__ float logsigf(float x) {
  return fminf(x, 0.f) - log1pf(expf(-fabsf(x)));
}

// ---- bf16 helpers (storage bf16, math fp32) ----
__device__ __forceinline__ float lo16(u32 u) { return __uint_as_float(u << 16); }
__device__ __forceinline__ float hi16(u32 u) { return __uint_as_float(u & 0xFFFF0000u); }
__device__ __forceinline__ u32 pk2(float a, float b) {  // RNE pack
  u32 ua = __float_as_uint(a), ub = __float_as_uint(b);
  u32 ra = (ua + 0x7FFFu + ((ua >> 16) & 1u)) >> 16;
  u32 rb = (ub + 0x7FFFu + ((ub >> 16) & 1u)) >> 16;
  return (ra & 0xFFFFu) | (rb << 16);
}
__device__ __forceinline__ float bfat(const u16* __restrict__ p, size_t off) {
  return __uint_as_float(((u32)p[off]) << 16);
}
__device__ __forceinline__ void accum8(float* a, float w, uint4 x) {
  a[0] += w * lo16(x.x); a[1] += w * hi16(x.x);
  a[2] += w * lo16(x.y); a[3] += w * hi16(x.y);
  a[4] += w * lo16(x.z); a[5] += w * hi16(x.z);
  a[6] += w * lo16(x.w); a[7] += w * hi16(x.w);
}
__device__ __forceinline__ uint4 pack8(const float* a, float w) {
  return make_uint4(pk2(w * a[0], w * a[1]), pk2(w * a[2], w * a[3]),
                    pk2(w * a[4], w * a[5]), pk2(w * a[6], w * a[7]));
}

// ================= CSR build via bucket binning =================
// seg 0 = tgt, 1 = aux0, 2 = aux1. Directed entry packed: (dst_local<<18)|src.

__global__ void hist_kernel(const int2* __restrict__ tgt, const int2* __restrict__ aux,
                            int E, int Nu, int BPS, int* __restrict__ bcur) {
  __shared__ int lh[NBK];
  int seg = blockIdx.x / BPS;
  int blk = blockIdx.x - seg * BPS;
  const int2* edges = (seg == 0) ? tgt : aux + (size_t)(seg - 1) * E;
  for (int b = threadIdx.x; b < NBK; b += 256) lh[b] = 0;
  __syncthreads();
  int e0 = blk * TILE_H;
  for (int k = threadIdx.x; k < TILE_H; k += 256) {
    int e = e0 + k;
    if (e < E) {
      int2 ed = edges[e];
      atomicAdd(&lh[ed.x >> BSHIFT], 1);
      atomicAdd(&lh[(ed.y + Nu) >> BSHIFT], 1);
    }
  }
  __syncthreads();
  for (int b = threadIdx.x; b < NBK; b += 256)
    if (lh[b]) atomicAdd(&bcur[seg * NBK + b], lh[b]);
}

__global__ void bscan_kernel(int* __restrict__ bcur) {
  int* b = bcur + blockIdx.x * NBK;
  int lane = threadIdx.x;
  int carry = 0;
  for (int base = 0; base < NBK; base += 64) {
    int i = base + lane;
    int v = b[i];
    int s = v;
    #pragma unroll
    for (int o = 1; o < 64; o <<= 1) {
      int t = __shfl_up(s, o);
      if (lane >= o) s += t;
    }
    b[i] = carry + s - v;
    carry += __shfl(s, 63);
  }
}

__global__ void bin_kernel(const int2* __restrict__ tgt, const int2* __restrict__ aux,
                           int E, int Nu, int BPS, int* __restrict__ bcur,
                           int* __restrict__ binned) {
  __shared__ int stage[2 * TILE_BIN];
  __shared__ int lh[NBK];
  __shared__ int loff[NBK];
  __shared__ int gb[NBK];
  __shared__ int wred[4];
  __shared__ int stot;
  int seg = blockIdx.x / BPS;
  int blk = blockIdx.x - seg * BPS;
  const int2* edges = (seg == 0) ? tgt : aux + (size_t)(seg - 1) * E;
  int* out = binned + (size_t)seg * 2 * E;
  int tid = threadIdx.x;
  for (int b = tid; b < NBK; b += 256) lh[b] = 0;
  __syncthreads();
  int e0 = blk * TILE_BIN;
  int pkv[16];
  int pb[16];
  int pr[16];
  #pragma unroll
  for (int it = 0; it < 8; ++it) {
    int e = e0 + tid + it * 256;
    bool ok = e < E;
    int2 ed = ok ? edges[e] : make_int2(0, -Nu);
    int u = ed.x, v = ed.y + Nu;
    int b1 = u >> BSHIFT, b2 = v >> BSHIFT;
    pkv[2 * it] = ((u & 255) << 18) | v;
    pb[2 * it] = b1;
    pr[2 * it] = ok ? atomicAdd(&lh[b1], 1) : 0;
    pkv[2 * it + 1] = ((v & 255) << 18) | u;
    pb[2 * it + 1] = b2;
    pr[2 * it + 1] = ok ? atomicAdd(&lh[b2], 1) : 0;
  }
  __syncthreads();
  int lane = tid & 63, wid = tid >> 6;
  int b4 = tid * 4;
  int v0 = lh[b4], v1 = lh[b4 + 1], v2 = lh[b4 + 2], v3 = lh[b4 + 3];
  int tsum = v0 + v1 + v2 + v3;
  int incl = tsum;
  #pragma unroll
  for (int o = 1; o < 64; o <<= 1) {
    int t = __shfl_up(incl, o);
    if (lane >= o) incl += t;
  }
  if (lane == 63) wred[wid] = incl;
  __syncthreads();
  int wbase = 0;
  for (int w = 0; w < wid; ++w) wbase += wred[w];
  int excl = wbase + incl - tsum;
  loff[b4] = excl;
  loff[b4 + 1] = excl + v0;
  loff[b4 + 2] = excl + v0 + v1;
  loff[b4 + 3] = excl + v0 + v1 + v2;
  if (tid == 255) stot = excl + tsum;
  #pragma unroll
  for (int j = 0; j < 4; ++j) {
    int b = b4 + j;
    int c = lh[b];
    gb[b] = c ? atomicAdd(&bcur[seg * NBK + b], c) : 0;
  }
  __syncthreads();
  #pragma unroll
  for (int it = 0; it < 16; ++it) {
    int e = e0 + tid + (it >> 1) * 256;
    if (e < E) stage[loff[pb[it]] + pr[it]] = pkv[it];
  }
  __syncthreads();
  int tot = stot;
  for (int k = tid; k < tot; k += 256) {
    int lo = 0, hi = NBK;
    while (lo < hi) {
      int mid = (lo + hi) >> 1;
      if (loff[mid] <= k) lo = mid + 1; else hi = mid;
    }
    int b = lo - 1;
    out[gb[b] + (k - loff[b])] = stage[k];
  }
}

__global__ void bucket_csr_kernel(const int* __restrict__ binned,
                                  const int* __restrict__ bend, int E2, int N, int NBKe,
                                  int* __restrict__ deg3, int* __restrict__ rp3,
                                  int* __restrict__ col_all) {
  __shared__ int ent[BCAP];
  __shared__ int cnt[256];
  __shared__ int off[256];
  __shared__ int wred[4];
  int seg = blockIdx.x / NBKe;
  int bkt = blockIdx.x - seg * NBKe;
  int node0 = bkt << BSHIFT;
  const int* bc = bend + seg * NBK;
  int start = (bkt == 0) ? 0 : bc[bkt - 1];
  int end = bc[bkt];
  int cntE = end - start;
  const int* src = binned + (size_t)seg * E2 + start;
  bool inLds = (cntE <= BCAP);
  if (inLds)
    for (int k = threadIdx.x; k < cntE; k += 256) ent[k] = src[k];
  cnt[threadIdx.x] = 0;
  __syncthreads();
  for (int k = threadIdx.x; k < cntE; k += 256) {
    int en = inLds ? ent[k] : src[k];
    atomicAdd(&cnt[en >> 18], 1);
  }
  __syncthreads();
  int lane = threadIdx.x & 63, wid = threadIdx.x >> 6;
  int v = cnt[threadIdx.x];
  int incl = v;
  #pragma unroll
  for (int o = 1; o < 64; o <<= 1) {
    int t = __shfl_up(incl, o);
    if (lane >= o) incl += t;
  }
  if (lane == 63) wred[wid] = incl;
  __syncthreads();
  int wbase = 0;
  for (int w = 0; w < wid; ++w) wbase += wred[w];
  off[threadIdx.x] = wbase + incl - v;
  int node = node0 + (int)threadIdx.x;
  if (node < N) {
    deg3[(size_t)seg * N + node] = v;
    rp3[(size_t)seg * (N + 1) + node] = start + wbase + incl - v;
  }
  if (bkt == 0 && threadIdx.x == 0) rp3[(size_t)seg * (N + 1) + N] = E2;
  __syncthreads();
  cnt[threadIdx.x] = 0;
  __syncthreads();
  int* col = col_all + (size_t)seg * E2 + start;
  for (int k = threadIdx.x; k < cntE; k += 256) {
    int en = inLds ? ent[k] : src[k];
    int lb = en >> 18;
    int pos = atomicAdd(&cnt[lb], 1);
    col[off[lb] + pos] = en & 0x3FFFF;
  }
}

__global__ void dinv_all_kernel(const int* __restrict__ deg3, float* __restrict__ dinv5,
                                int N) {
  int n = blockIdx.x * blockDim.x + threadIdx.x;
  if (n >= N) return;
  int dt = deg3[n], d0 = deg3[N + n], d1 = deg3[2 * N + n];
  dinv5[n]         = dt ? rsqrtf((float)dt) : 0.f;
  dinv5[N + n]     = d0 ? rsqrtf((float)d0) : 0.f;
  dinv5[2 * N + n] = d1 ? rsqrtf((float)d1) : 0.f;
  int c0 = dt + d0, c1 = dt + d1;
  dinv5[3 * N + n] = c0 ? rsqrtf((float)c0) : 0.f;
  dinv5[4 * N + n] = c1 ? rsqrtf((float)c1) : 0.f;
}

__global__ void cvt_emb_kernel(const float2* __restrict__ ue, long nu2,
                               const float2* __restrict__ ie, long ni2,
                               u32* __restrict__ emb) {
  long i = (long)blockIdx.x * blockDim.x + threadIdx.x;
  if (i >= nu2 + ni2) return;
  float2 v = (i < nu2) ? ue[i] : ie[i - nu2];
  emb[i] = pk2(v.x, v.y);
}

// ================= dense propagation (bf16 rows) =================

// layer-1 for BOTH idx: Ba0/Ba1 (planar) = aux L1, Bc0/Bc1 (planar) = comb L1.
// tgt rows read ONCE. 4 lanes/node. 4-edge unroll for MLP.
__global__ void gather_fused_all_kernel(const int* __restrict__ rp3,
                                        const int* __restrict__ col_all,
                                        const float* __restrict__ dinv5,
                                        const uint4* __restrict__ emb,
                                        uint4* __restrict__ BaAll, uint4* __restrict__ BcAll,
                                        int N, int E2) {
  const int* rpA0 = rp3 + (size_t)1 * (N + 1);
  const int* rpA1 = rp3 + (size_t)2 * (N + 1);
  const int* colA0 = col_all + (size_t)1 * E2;
  const int* colA1 = col_all + (size_t)2 * E2;
  const float* dvA0 = dinv5 + (size_t)1 * N;
  const float* dvA1 = dinv5 + (size_t)2 * N;
  const float* dvC0 = dinv5 + (size_t)3 * N;
  const float* dvC1 = dinv5 + (size_t)4 * N;
  int t = blockIdx.x * blockDim.x + threadIdx.x;
  int n = t >> 2;
  if (n >= N) return;
  int lane = t & 3;
  float aA0[8] = {0, 0, 0, 0, 0, 0, 0, 0};
  float aA1[8] = {0, 0, 0, 0, 0, 0, 0, 0};
  float aC0[8] = {0, 0, 0, 0, 0, 0, 0, 0};
  float aC1[8] = {0, 0, 0, 0, 0, 0, 0, 0};
  // aux0 edges -> Ba0, Bc0 (4-edge unroll)
  int s = rpA0[n], e = rpA0[n + 1];
  int j = s;
  for (; j + 3 < e; j += 4) {
    int c0 = colA0[j], c1 = colA0[j + 1], c2 = colA0[j + 2], c3 = colA0[j + 3];
    uint4 x0 = emb[(size_t)c0 * 4 + lane];
    uint4 x1 = emb[(size_t)c1 * 4 + lane];
    uint4 x2 = emb[(size_t)c2 * 4 + lane];
    uint4 x3 = emb[(size_t)c3 * 4 + lane];
    accum8(aA0, dvA0[c0], x0); accum8(aC0, dvC0[c0], x0);
    accum8(aA0, dvA0[c1], x1); accum8(aC0, dvC0[c1], x1);
    accum8(aA0, dvA0[c2], x2); accum8(aC0, dvC0[c2], x2);
    accum8(aA0, dvA0[c3], x3); accum8(aC0, dvC0[c3], x3);
  }
  for (; j < e; ++j) {
    int c = colA0[j];
    uint4 x = emb[(size_t)c * 4 + lane];
    accum8(aA0, dvA0[c], x); accum8(aC0, dvC0[c], x);
  }
  // aux1 edges -> Ba1, Bc1
  s = rpA1[n]; e = rpA1[n + 1];
  j = s;
  for (; j + 3 < e; j += 4) {
    int c0 = colA1[j], c1 = colA1[j + 1], c2 = colA1[j + 2], c3 = colA1[j + 3];
    uint4 x0 = emb[(size_t)c0 * 4 + lane];
    uint4 x1 = emb[(size_t)c1 * 4 + lane];
    uint4 x2 = emb[(size_t)c2 * 4 + lane];
    uint4 x3 = emb[(size_t)c3 * 4 + lane];
    accum8(aA1, dvA1[c0], x0); accum8(aC1, dvC1[c0], x0);
    accum8(aA1, dvA1[c1], x1); accum8(aC1, dvC1[c1], x1);
    accum8(aA1, dvA1[c2], x2); accum8(aC1, dvC1[c2], x2);
    accum8(aA1, dvA1[c3], x3); accum8(aC1, dvC1[c3], x3);
  }
  for (; j < e; ++j) {
    int c = colA1[j];
    uint4 x = emb[(size_t)c * 4 + lane];
    accum8(aA1, dvA1[c], x); accum8(aC1, dvC1[c], x);
  }
  // tgt edges -> Bc0, Bc1 (rows read once for both idx)
  s = rp3[n]; e = rp3[n + 1];
  j = s;
  for (; j + 3 < e; j += 4) {
    int c0 = col_all[j], c1 = col_all[j + 1], c2 = col_all[j + 2], c3 = col_all[j + 3];
    uint4 x0 = emb[(size_t)c0 * 4 + lane];
    uint4 x1 = emb[(size_t)c1 * 4 + lane];
    uint4 x2 = emb[(size_t)c2 * 4 + lane];
    uint4 x3 = emb[(size_t)c3 * 4 + lane];
    accum8(aC0, dvC0[c0], x0); accum8(aC1, dvC1[c0], x0);
    accum8(aC0, dvC0[c1], x1); accum8(aC1, dvC1[c1], x1);
    accum8(aC0, dvC0[c2], x2); accum8(aC1, dvC1[c2], x2);
    accum8(aC0, dvC0[c3], x3); accum8(aC1, dvC1[c3], x3);
  }
  for (; j < e; ++j) {
    int c = col_all[j];
    uint4 x = emb[(size_t)c * 4 + lane];
    accum8(aC0, dvC0[c], x); accum8(aC1, dvC1[c], x);
  }
  size_t o = (size_t)n * 4 + lane;
  size_t rowN4 = (size_t)N * 4;
  BaAll[o] = pack8(aA0, dvA0[n]);
  BaAll[rowN4 + o] = pack8(aA1, dvA1[n]);
  BcAll[o] = pack8(aC0, dvC0[n]);
  BcAll[rowN4 + o] = pack8(aC1, dvC1[n]);
}

// aux L2 + avg: A(idx) = (EMB + Ba + dinv*gather(Ba))/3.
// A written INTERLEAVED: node n row = [idx0 64B][idx1 64B]. 4-edge unroll.
__global__ void gather_avg_kernel(const int* __restrict__ rp3, const int* __restrict__ col_all,
                                  const float* __restrict__ dinv5,
                                  const uint4* __restrict__ emb,
                                  const uint4* __restrict__ BaAll, uint4* __restrict__ AI,
                                  int N, int E2) {
  int idx = blockIdx.y;
  const int* rp = rp3 + (size_t)(1 + idx) * (N + 1);
  const int* col = col_all + (size_t)(1 + idx) * E2;
  const float* dv = dinv5 + (size_t)(1 + idx) * N;
  const uint4* cur = BaAll + (size_t)idx * N * 4;
  int t = blockIdx.x * blockDim.x + threadIdx.x;
  int n = t >> 2;
  if (n >= N) return;
  int lane = t & 3;
  float acc[8] = {0, 0, 0, 0, 0, 0, 0, 0};
  int s = rp[n], e = rp[n + 1];
  int j = s;
  for (; j + 3 < e; j += 4) {
    int c0 = col[j], c1 = col[j + 1], c2 = col[j + 2], c3 = col[j + 3];
    float w0 = dv[c0], w1 = dv[c1], w2 = dv[c2], w3 = dv[c3];
    uint4 x0 = cur[(size_t)c0 * 4 + lane];
    uint4 x1 = cur[(size_t)c1 * 4 + lane];
    uint4 x2 = cur[(size_t)c2 * 4 + lane];
    uint4 x3 = cur[(size_t)c3 * 4 + lane];
    accum8(acc, w0, x0);
    accum8(acc, w1, x1);
    accum8(acc, w2, x2);
    accum8(acc, w3, x3);
  }
  for (; j < e; ++j) {
    int c = col[j];
    float w = dv[c];
    uint4 x = cur[(size_t)c * 4 + lane];
    accum8(acc, w, x);
  }
  float wn = dv[n];
  uint4 e4 = emb[(size_t)n * 4 + lane];
  uint4 b4 = cur[(size_t)n * 4 + lane];
  float r[8];
  r[0] = (lo16(e4.x) + lo16(b4.x) + wn * acc[0]) * (1.f / 3.f);
  r[1] = (hi16(e4.x) + hi16(b4.x) + wn * acc[1]) * (1.f / 3.f);
  r[2] = (lo16(e4.y) + lo16(b4.y) + wn * acc[2]) * (1.f / 3.f);
  r[3] = (hi16(e4.y) + hi16(b4.y) + wn * acc[3]) * (1.f / 3.f);
  r[4] = (lo16(e4.z) + lo16(b4.z) + wn * acc[4]) * (1.f / 3.f);
  r[5] = (hi16(e4.z) + hi16(b4.z) + wn * acc[5]) * (1.f / 3.f);
  r[6] = (lo16(e4.w) + lo16(b4.w) + wn * acc[6]) * (1.f / 3.f);
  r[7] = (hi16(e4.w) + hi16(b4.w) + wn * acc[7]) * (1.f / 3.f);
  AI[(size_t)n * 8 + idx * 4 + lane] = pack8(r, 1.f);
}

// de layer-1 for BOTH idx in ONE tgt pass: 8 lanes/node, lane/4 = idx half.
// Reads interleaved A (128 B/row shared), writes interleaved De. 4-edge unroll.
__global__ void de_gather_kernel(const int* __restrict__ rp3, const int* __restrict__ col_all,
                                 const float* __restrict__ dinv5,
                                 const uint4* __restrict__ AI, uint4* __restrict__ DeI,
                                 int N) {
  int t = blockIdx.x * blockDim.x + threadIdx.x;
  int n = t >> 3;
  if (n >= N) return;
  int lane = t & 7;
  float acc[8] = {0, 0, 0, 0, 0, 0, 0, 0};
  int s = rp3[n], e = rp3[n + 1];
  int j = s;
  for (; j + 3 < e; j += 4) {
    int c0 = col_all[j], c1 = col_all[j + 1], c2 = col_all[j + 2], c3 = col_all[j + 3];
    float w0 = dinv5[c0], w1 = dinv5[c1], w2 = dinv5[c2], w3 = dinv5[c3];
    uint4 x0 = AI[(size_t)c0 * 8 + lane];
    uint4 x1 = AI[(size_t)c1 * 8 + lane];
    uint4 x2 = AI[(size_t)c2 * 8 + lane];
    uint4 x3 = AI[(size_t)c3 * 8 + lane];
    accum8(acc, w0, x0);
    accum8(acc, w1, x1);
    accum8(acc, w2, x2);
    accum8(acc, w3, x3);
  }
  for (; j < e; ++j) {
    int c = col_all[j];
    float w = dinv5[c];
    uint4 x = AI[(size_t)c * 8 + lane];
    accum8(acc, w, x);
  }
  DeI[(size_t)n * 8 + lane] = pack8(acc, dinv5[n]);
}

// ================= sparse L2 + score (bf16 rows) =================

__device__ __forceinline__ float fdim2(const int* __restrict__ rpA, const int* __restrict__ colA,
                                       const int* __restrict__ rpT, const int* __restrict__ colT,
                                       const float* __restrict__ dv,
                                       const u16* __restrict__ base, const u16* __restrict__ L1,
                                       int r, int d) {
  float acc = 0.f;
  for (int j = rpA[r]; j < rpA[r + 1]; ++j) {
    int c = colA[j];
    acc += dv[c] * bfat(L1, (size_t)c * D + d);
  }
  for (int j = rpT[r]; j < rpT[r + 1]; ++j) {
    int c = colT[j];
    acc += dv[c] * bfat(L1, (size_t)c * D + d);
  }
  return (bfat(base, (size_t)r * D + d) + bfat(L1, (size_t)r * D + d) + dv[r] * acc) * (1.f / 3.f);
}

__device__ __forceinline__ float fdim1i(const int* __restrict__ rp, const int* __restrict__ col,
                                        const float* __restrict__ dv,
                                        const u16* __restrict__ base, const u16* __restrict__ L1,
                                        int r, int di) {
  float acc = 0.f;
  for (int j = rp[r]; j < rp[r + 1]; ++j) {
    int c = col[j];
    acc += dv[c] * bfat(L1, (size_t)c * 64 + di);
  }
  return (bfat(base, (size_t)r * 64 + di) + bfat(L1, (size_t)r * 64 + di) + dv[r] * acc) * (1.f / 3.f);
}

__global__ void ce_sparse_kernel(const int* __restrict__ rp3, const int* __restrict__ col_all,
                                 const float* __restrict__ dinv5,
                                 const u32* __restrict__ EMBu, const u32* __restrict__ BcAll,
                                 const int* __restrict__ batch, int Bsz, int Nu, int N, int E2,
                                 float* __restrict__ cps, float* __restrict__ cns) {
  int idx = blockIdx.y;
  const int* rpA = rp3 + (size_t)(1 + idx) * (N + 1);
  const int* colA = col_all + (size_t)(1 + idx) * E2;
  const float* dv = dinv5 + (size_t)(3 + idx) * N;
  const u16* base = (const u16*)EMBu;
  const u16* L1 = (const u16*)(BcAll + (size_t)idx * N * ROWU);
  float* outp = cps + (size_t)idx * Bsz;
  float* outn = cns + (size_t)idx * Bsz;
  int t = blockIdx.x * blockDim.x + threadIdx.x;
  int b = t >> 5, d = t & 31;
  if (b >= Bsz) return;
  int u = batch[b * 9 + 0];
  int p = batch[b * 9 + 1] + Nu;
  int n = batch[b * 9 + 2] + Nu;
  float uv = fdim2(rpA, colA, rp3, col_all, dv, base, L1, u, d);
  float pv = fdim2(rpA, colA, rp3, col_all, dv, base, L1, p, d);
  float nv = fdim2(rpA, colA, rp3, col_all, dv, base, L1, n, d);
  float sp = uv * pv, sn = uv * nv;
  #pragma unroll
  for (int o = 16; o > 0; o >>= 1) {
    sp += __shfl_down(sp, o, 32);
    sn += __shfl_down(sn, o, 32);
  }
  if (d == 0) {
    outp[b] = fmaxf(sp, 0.f);
    outn[b] = fmaxf(sn, 0.f);
  }
}

__global__ void de_sparse_kernel(const int* __restrict__ rp3, const int* __restrict__ col_all,
                                 const float* __restrict__ dinv5,
                                 const u32* __restrict__ AI, const u32* __restrict__ DeI,
                                 const int* __restrict__ batch, int Bsz, int Nu, int N,
                                 float* __restrict__ dps, float* __restrict__ dns) {
  int idx = blockIdx.y;
  const u16* base = (const u16*)AI;
  const u16* L1 = (const u16*)DeI;
  float* outp = dps + (size_t)idx * Bsz;
  float* outn = dns + (size_t)idx * Bsz;
  int t = blockIdx.x * blockDim.x + threadIdx.x;
  int b = t >> 5, d = t & 31;
  if (b >= Bsz) return;
  int di = idx * 32 + d;
  int u = batch[b * 9 + 0];
  int p = batch[b * 9 + 1] + Nu;
  int n = batch[b * 9 + 2] + Nu;
  float uv = fdim1i(rp3, col_all, dinv5, base, L1, u, di);
  float pv = fdim1i(rp3, col_all, dinv5, base, L1, p, di);
  float nv = fdim1i(rp3, col_all, dinv5, base, L1, n, di);
  float sp = uv * pv, sn = uv * nv;
  #pragma unroll
  for (int o = 16; o > 0; o >>= 1) {
    sp += __shfl_down(sp, o, 32);
    sn += __shfl_down(sn, o, 32);
  }
  if (d == 0) {
    outp[b] = fmaxf(sp, 0.f);
    outn[b] = fmaxf(sn, 0.f);
  }
}

// ================= batch scores / losses on interleaved A (bf16) =================

__device__ __forceinline__ float dotrow(const u32* __restrict__ a, const u32* __restrict__ b) {
  float s = 0.f;
  #pragma unroll
  for (int k = 0; k < ROWU; ++k) {
    u32 x = a[k], y = b[k];
    s += lo16(x) * lo16(y) + hi16(x) * hi16(y);
  }
  return s;
}

__global__ void score_aux_kernel(const u32* __restrict__ AI, const int* __restrict__ batch,
                                 int Bsz, int Nu, int N, float* __restrict__ aps,
                                 float* __restrict__ ans_, float* __restrict__ accs) {
  int idx = blockIdx.y;
  const u32* A = AI + (size_t)idx * ROWU;  // interleaved: row r at r*32 + idx*16
  float* outp = aps + (size_t)idx * Bsz;
  float* outn = ans_ + (size_t)idx * Bsz;
  int b = blockIdx.x * blockDim.x + threadIdx.x;
  float l = 0.f;
  if (b < Bsz) {
    int u = batch[b * 9 + 0];
    int p = batch[b * 9 + 1] + Nu;
    int n = batch[b * 9 + 2] + Nu;
    const u32* ur = A + (size_t)u * 32;
    outp[b] = fmaxf(dotrow(ur, A + (size_t)p * 32), 0.f);
    outn[b] = fmaxf(dotrow(ur, A + (size_t)n * 32), 0.f);
    const int* r = batch + b * 9 + 3 * (1 + idx);
    const u32* aur = A + (size_t)r[0] * 32;
    float ps = dotrow(aur, A + (size_t)(r[1] + Nu) * 32);
    float ns = dotrow(aur, A + (size_t)(r[2] + Nu) * 32);
    l = -logsigf(ps - ns);
  }
  for (int o = 32; o > 0; o >>= 1) l += __shfl_down(l, o);
  if ((threadIdx.x & 63) == 0) atomicAdd(&accs[idx], l);
}

__global__ void recloss_kernel(const float* __restrict__ cps, const float* __restrict__ cns,
                               const float* __restrict__ aps, const float* __restrict__ ans_,
                               const float* __restrict__ dps, const float* __restrict__ dns,
                               int Bsz, int NA, float* __restrict__ acc) {
  int b = blockIdx.x * blockDim.x + threadIdx.x;
  float l = 0.f;
  if (b < Bsz) {
    float dp = 0.f, dn = 0.f, cap = 0.f, can = 0.f;
    for (int i = 0; i < NA; ++i) {
      dp += dps[i * Bsz + b];
      dn += dns[i * Bsz + b];
      cap += cps[i * Bsz + b] * aps[i * Bsz + b];
      can += cns[i * Bsz + b] * ans_[i * Bsz + b];
    }
    l = -logsigf(dp * cap - dn * can);
  }
  for (int o = 32; o > 0; o >>= 1) l += __shfl_down(l, o);
  if ((threadIdx.x & 63) == 0) atomicAdd(acc, l);
}

__global__ void sumsq2_kernel(const float4* __restrict__ xu, int n4u,
                              const float4* __restrict__ xi, int n4i,
                              float* __restrict__ accU, float* __restrict__ accI) {
  __shared__ float redU[4], redI[4];
  int tid = threadIdx.x;
  int gid = blockIdx.x * blockDim.x + tid;
  int stride = gridDim.x * blockDim.x;
  float su = 0.f, si = 0.f;
  for (int i = gid; i < n4u; i += stride) {
    float4 v = xu[i];
    su += v.x * v.x + v.y * v.y + v.z * v.z + v.w * v.w;
  }
  for (int i = gid; i < n4i; i += stride) {
    float4 v = xi[i];
    si += v.x * v.x + v.y * v.y + v.z * v.z + v.w * v.w;
  }
  for (int o = 32; o > 0; o >>= 1) {
    su += __shfl_down(su, o);
    si += __shfl_down(si, o);
  }
  if ((tid & 63) == 0) { redU[tid >> 6] = su; redI[tid >> 6] = si; }
  __syncthreads();
  if (tid == 0) {
    atomicAdd(accU, redU[0] + redU[1] + redU[2] + redU[3]);
    atomicAdd(accI, redI[0] + redI[1] + redI[2] + redI[3]);
  }
}

__global__ void final_kernel(const float* __restrict__ accs, int Bsz, int NA, int NiRows,
                             float* __restrict__ out) {
  float rec = accs[NA] / (float)Bsz;
  float aux = 0.f;
  for (int i = 0; i < NA; ++i) aux += accs[i] / (float)Bsz;
  aux /= (float)NA;
  float embl = (sqrtf(accs[NA + 1]) + sqrtf(accs[NA + 2])) / (float)NiRows;
  out[0] = rec + 0.5f * aux + 1e-4f * embl;
}

extern "C" void kernel_launch(void* const* d_in, const int* in_sizes, int n_in,
                              void* d_out, int out_size, void* d_ws, size_t ws_size,
                              hipStream_t stream) {
  const float* user_emb = (const float*)d_in[0];
  const float* item_emb = (const float*)d_in[1];
  const int* batch = (const int*)d_in[2];
  const int* aux_edges = (const int*)d_in[3];
  const int* tgt_edges = (const int*)d_in[4];

  const int NuRows = in_sizes[0] / D;          // 100001
  const int NiRows = in_sizes[1] / D;          // 50001
  const int Bsz = in_sizes[2] / 9;             // 4096
  const int E = in_sizes[4] / 2;               // 1,000,000
  const int NA = in_sizes[3] / (2 * E);        // 2
  const int N = NuRows + NiRows;               // 150002 < 2^18 (pack invariant)
  const int E2 = 2 * E;
  const size_t rowH = (size_t)N * ROWU;
  const int BPS_H = (E + TILE_H - 1) / TILE_H;
  const int BPS_B = (E + TILE_BIN - 1) / TILE_BIN;
  const int NBKe = (N + (1 << BSHIFT) - 1) >> BSHIFT;

  // ---- workspace layout ----
  u32* EMBu = (u32*)d_ws;                 // rowH (planar)
  u32* AI = EMBu + rowH;                  // 2*rowH (INTERLEAVED per node)
  u32* BaAll = AI + 2 * rowH;             // 2*rowH (planar aux L1; later interleaved De)
  u32* BcAll = BaAll + 2 * rowH;          // 2*rowH (planar comb L1)
  int* deg3 = (int*)(BcAll + 2 * rowH);           // 3*N
  float* dinv5 = (float*)(deg3 + 3 * (size_t)N);  // 5*N
  int* rp3 = (int*)(dinv5 + 5 * (size_t)N);       // 3*(N+1)
  int* bcur = rp3 + 3 * (size_t)(N + 1);          // 3*NBK
  int* col_all = bcur + 3 * (size_t)NBK;          // 3*2E
  float* cps = (float*)(col_all + 3 * (size_t)E2);
  float* cns = cps + (size_t)NA * Bsz;
  float* aps = cns + (size_t)NA * Bsz;
  float* ans_ = aps + (size_t)NA * Bsz;
  float* dps = ans_ + (size_t)NA * Bsz;
  float* dns = dps + (size_t)NA * Bsz;
  float* accs = dns + (size_t)NA * Bsz;           // [NA aux][rec][sumsq_u][sumsq_i]
  int* binned = (int*)AI;  // 24 MB alias spanning AI+BaAll; dead before gathers

  const int TB = 256;
  const int gN = (N + TB - 1) / TB;
  const int gN4 = (N * 4 + TB - 1) / TB;
  const int gN8 = (N * 8 + TB - 1) / TB;
  const int gB = (Bsz + TB - 1) / TB;
  const int gB32 = (Bsz * 32 + TB - 1) / TB;
  const long nu2 = (long)NuRows * ROWU;
  const long ni2 = (long)NiRows * ROWU;
  const int gCvt = (int)((nu2 + ni2 + TB - 1) / TB);

  cvt_emb_kernel<<<gCvt, TB, 0, stream>>>((const float2*)user_emb, nu2,
                                          (const float2*)item_emb, ni2, EMBu);

  // ---- binned CSR build ----
  hipMemsetAsync(bcur, 0, 3 * (size_t)NBK * sizeof(int), stream);
  hist_kernel<<<3 * BPS_H, TB, 0, stream>>>((const int2*)tgt_edges, (const int2*)aux_edges,
                                            E, NuRows, BPS_H, bcur);
  bscan_kernel<<<3, 64, 0, stream>>>(bcur);
  bin_kernel<<<3 * BPS_B, TB, 0, stream>>>((const int2*)tgt_edges, (const int2*)aux_edges,
                                           E, NuRows, BPS_B, bcur, binned);
  bucket_csr_kernel<<<3 * NBKe, TB, 0, stream>>>(binned, bcur, E2, N, NBKe,
                                                 deg3, rp3, col_all);
  dinv_all_kernel<<<gN, TB, 0, stream>>>(deg3, dinv5, N);

  hipMemsetAsync(accs, 0, (size_t)(NA + 3) * sizeof(float), stream);

  dim3 gridG(gN4, NA), gridB(gB, NA), gridS(gB32, NA);

  gather_fused_all_kernel<<<gN4, TB, 0, stream>>>(rp3, col_all, dinv5, (const uint4*)EMBu,
                                                  (uint4*)BaAll, (uint4*)BcAll, N, E2);
  gather_avg_kernel<<<gridG, TB, 0, stream>>>(rp3, col_all, dinv5, (const uint4*)EMBu,
                                              (const uint4*)BaAll, (uint4*)AI, N, E2);
  score_aux_kernel<<<gridB, TB, 0, stream>>>(AI, batch, Bsz, NuRows, N, aps, ans_, accs);
  ce_sparse_kernel<<<gridS, TB, 0, stream>>>(rp3, col_all, dinv5, EMBu, BcAll,
                                             batch, Bsz, NuRows, N, E2, cps, cns);
  de_gather_kernel<<<gN8, TB, 0, stream>>>(rp3, col_all, dinv5, (const uint4*)AI,
                                           (uint4*)BaAll, N);
  de_sparse_kernel<<<gridS, TB, 0, stream>>>(rp3, col_all, dinv5, AI, BaAll,
                                             batch, Bsz, NuRows, N, dps, dns);

  sumsq2_kernel<<<104, TB, 0, stream>>>((const float4*)user_emb,
                                        (int)((size_t)NuRows * D / 4),
                                        (const float4*)item_emb,
                                        (int)((size_t)NiRows * D / 4),
                                        accs + NA + 1, accs + NA + 2);
  recloss_kernel<<<gB, TB, 0, stream>>>(cps, cns, aps, ans_, dps, dns, Bsz, NA, accs + NA);
  final_kernel<<<1, 1, 0, stream>>>(accs, Bsz, NA, NiRows, (float*)d_out);
}